// Round 11
// baseline (276.835 us; speedup 1.0000x reference)
//
#include <hip/hip_runtime.h>
#include <hip/hip_bf16.h>
#include <cstdint>

#define N_NODES 4096
#define STRIDE  384      // max degree cap (Binom(4096,0.05): mean 205, 12 sigma)
#define NPAIRS_MAX 192
#define QMAX    128      // per-quarter degree cap in build_nbr
#define WROW    400      // s_w16 head-row stride (u16): 800 B, 16B-aligned

typedef _Float16 half2v __attribute__((ext_vector_type(2)));
typedef _Float16 v4h __attribute__((ext_vector_type(4)));
typedef _Float16 v8h __attribute__((ext_vector_type(8)));
typedef float    v4f __attribute__((ext_vector_type(4)));
typedef unsigned u4v __attribute__((ext_vector_type(4)));   // clang-native for nt loads

// ---- fp16 helpers ---------------------------------------------------------
__device__ __forceinline__ float f16lo(unsigned u) {
    half2v h = __builtin_bit_cast(half2v, u); return (float)h.x;
}
__device__ __forceinline__ float f16hi(unsigned u) {
    half2v h = __builtin_bit_cast(half2v, u); return (float)h.y;
}
__device__ __forceinline__ unsigned pk_lo(unsigned a, unsigned b) {
    return __builtin_amdgcn_perm(b, a, 0x05040100u);
}
__device__ __forceinline__ unsigned pk_hi(unsigned a, unsigned b) {
    return __builtin_amdgcn_perm(b, a, 0x07060302u);
}
__device__ __forceinline__ float fdot2f(unsigned v, unsigned w, float acc) {
    return __builtin_amdgcn_fdot2(__builtin_bit_cast(half2v, v),
                                  __builtin_bit_cast(half2v, w), acc, false);
}
__device__ __forceinline__ float lrelu02(float s) { return (s > 0.f) ? s : 0.2f * s; }
__device__ __forceinline__ float lrelu01(float s) { return (s > 0.f) ? s : 0.01f * s; }

// ---------------------------------------------------------------------------
// 1. Fused setup: neighbor-list compaction + fp16 prep + score-acc zeroing.
// ---------------------------------------------------------------------------
__global__ __launch_bounds__(256) void setup_kernel(
    const float* __restrict__ adj, unsigned short* __restrict__ nbr,
    int* __restrict__ cnt,
    const float* __restrict__ x, const float* __restrict__ w1,
    const float* __restrict__ w2, _Float16* __restrict__ x16,
    _Float16* __restrict__ w1T, _Float16* __restrict__ w2T,
    float* __restrict__ as2, float* __restrict__ ad2) {
    const int b = blockIdx.x, t = threadIdx.x;
    if (b < 4096) {
        const int i    = b;
        const int wv   = t >> 6;
        const int lane = t & 63;
        __shared__ unsigned short s_buf[4][QMAX];
        __shared__ int s_cnt[4];
        const float4* row = (const float4*)(adj + (size_t)i * N_NODES);
        int base = 0;
#pragma unroll
        for (int it = 0; it < 4; it++) {
            float4 v = row[wv * 256 + it * 64 + lane];
            float e4[4] = {v.x, v.y, v.z, v.w};
            unsigned long long m4[4];
#pragma unroll
            for (int e = 0; e < 4; e++) m4[e] = __ballot(e4[e] != 0.0f);
#pragma unroll
            for (int e = 0; e < 4; e++) {
                int prefix = __popcll(m4[e] & ((1ull << lane) - 1ull));
                int pos = base + prefix;
                if (e4[e] != 0.0f && pos < QMAX)
                    s_buf[wv][pos] = (unsigned short)(wv * 1024 + (it * 64 + lane) * 4 + e);
                base += __popcll(m4[e]);
            }
        }
        if (lane == 0) s_cnt[wv] = (base < QMAX) ? base : QMAX;
        __syncthreads();
        const int c0 = s_cnt[0], c1 = s_cnt[1], c2 = s_cnt[2], c3 = s_cnt[3];
        const int o1 = c0, o2 = c0 + c1, o3 = o2 + c2;
        int total = o3 + c3;
        if (total > STRIDE) total = STRIDE;
        for (int k = t; k < total; k += 256) {
            int w, loc;
            if      (k < o1) { w = 0; loc = k; }
            else if (k < o2) { w = 1; loc = k - o1; }
            else if (k < o3) { w = 2; loc = k - o2; }
            else             { w = 3; loc = k - o3; }
            nbr[(size_t)i * STRIDE + k] = s_buf[w][loc];
        }
        if (t == 0) cnt[i] = total;
    } else if (b < 5120) {                // x: 4096*256 elems, 4/thread
        const int idx = (b - 4096) * 1024 + t * 4;
        float4 v = *(const float4*)(x + idx);
        v4h h = { (_Float16)v.x, (_Float16)v.y, (_Float16)v.z, (_Float16)v.w };
        *(v4h*)(x16 + idx) = h;
    } else if (b < 5632) {                // w1T[512][256] <- w1[256][512]
        const int idx = (b - 5120) * 256 + t;
        const int n = idx >> 8, k = idx & 255;
        w1T[idx] = (_Float16)w1[k * 512 + n];
    } else if (b < 5792) {                // w2T[128][512] <- w2[512][128]
        const int idx = (b - 5632) * 410;
        const int e   = idx + t;
        for (int q = e; q < idx + 410 && q < 65536; q += 256) {
            const int n = q >> 9, k = q & 511;
            w2T[q] = (_Float16)w2[k * 128 + n];
        }
    } else {                              // zero as2/ad2
        const int idx = (b - 5792) * 256 + t;
        as2[idx] = 0.f;
        ad2[idx] = 0.f;
    }
}

// ---------------------------------------------------------------------------
// 2. MFMA GEMM (wave-strip over full K), fp16 in / fp32 accum; fused scores.
// ---------------------------------------------------------------------------
template<int KCH, int NSUB, int H>
__global__ __launch_bounds__(256) void gemm_mfma_kernel(
    const _Float16* __restrict__ A16, const _Float16* __restrict__ BT16,
    _Float16* __restrict__ C16,
    const float* __restrict__ att_s, const float* __restrict__ att_d,
    float* __restrict__ as_, float* __restrict__ ad_, int N) {
    const int K    = KCH * 32;
    const int wid  = blockIdx.x * 4 + (threadIdx.x >> 6);
    const int lane = threadIdx.x & 63;
    const int quad = lane >> 4, l16 = lane & 15;
    const int ntiles = N / (16 * NSUB);
    const int m0 = (wid / ntiles) * 16;
    const int n0 = (wid % ntiles) * (16 * NSUB);

    v8h a[KCH];
    const v8h* arow = (const v8h*)(A16 + (size_t)(m0 + l16) * K + quad * 8);
#pragma unroll
    for (int c = 0; c < KCH; c++) a[c] = arow[c * 4];

    float ps[4] = {}, pd[4] = {};
#pragma unroll
    for (int s = 0; s < NSUB; s++) {
        const int n = n0 + s * 16 + l16;
        const v8h* brow = (const v8h*)(BT16 + (size_t)n * K + quad * 8);
        v4f acc = {0.f, 0.f, 0.f, 0.f};
#pragma unroll
        for (int c = 0; c < KCH; c++)
            acc = __builtin_amdgcn_mfma_f32_16x16x32_f16(a[c], brow[c * 4], acc, 0, 0, 0);
        const float sa = att_s[n], sd = att_d[n];
#pragma unroll
        for (int r = 0; r < 4; r++) {
            C16[(size_t)(m0 + quad * 4 + r) * N + n] = (_Float16)acc[r];
            ps[r] += acc[r] * sa;
            pd[r] += acc[r] * sd;
        }
    }
#pragma unroll
    for (int r = 0; r < 4; r++) {
#pragma unroll
        for (int off = 1; off < 16; off <<= 1) {
            ps[r] += __shfl_xor(ps[r], off);
            pd[r] += __shfl_xor(pd[r], off);
        }
    }
    if (l16 == 0) {
#pragma unroll
        for (int r = 0; r < 4; r++) {
            const int row = m0 + quad * 4 + r;
            if (H > 1) {
                const int head = n0 >> 6;
                as_[row * H + head] = ps[r];
                ad_[row * H + head] = pd[r];
            } else {
                atomicAdd(&as_[row], ps[r]);
                atomicAdd(&ad_[row], pd[r]);
            }
        }
    }
}

// ---------------------------------------------------------------------------
// 3. Layer-1 sparse aggregate, flash-split, deep-pipelined gather:
//    rows padded to 64-edge multiples (pad w=0, id=0 -> exact); pass-3
//    processes 2 quads (16 edges) with all 16 nt-loads in flight.
// ---------------------------------------------------------------------------
__global__ __launch_bounds__(128, 4) void attn1_kernel(
    const _Float16* __restrict__ h1g, const float* __restrict__ asrc,
    const float* __restrict__ adst, const unsigned short* __restrict__ nbr,
    const int* __restrict__ cnt, const float* __restrict__ b1,
    _Float16* __restrict__ out1f16) {
    const int i    = blockIdx.x;
    const int wv   = threadIdx.x >> 6;
    const int lane = threadIdx.x & 63;
    const int hd   = lane >> 3;               // head of this lane (8 ch each)
    __shared__ __align__(16) unsigned s_nb[NPAIRS_MAX];
    __shared__ __align__(16) unsigned short s_w16[8][WROW];
    __shared__ __align__(16) float s_comb[512];
    __shared__ float s_ml[2][2][8];

    const int n     = cnt[i];
    const int npadE = (n + 63) & ~63;         // 64-edge multiple (<= 384)
    const int npadp = npadE >> 1;
    const int nq    = npadE >> 3;             // quads (multiple of 8)

    // stage OWNED pair chunks (32 pairs per 64-edge chunk, interleaved by wv)
    const unsigned* nbr32 = (const unsigned*)(nbr + (size_t)i * STRIDE);
    for (int k0 = wv * 32; k0 < npadp; k0 += 128) {
        const int k = k0 + (lane & 31) + ((lane >= 32) ? 64 : 0);
        if (k < npadp) {
            unsigned v = 0u;
            if (2 * k + 1 < n)  v = nbr32[k];
            else if (2 * k < n) v = nbr32[k] & 0xffffu;
            s_nb[k] = v;
        }
    }

    float ad8[8];
    {
        const float4 a0 = *(const float4*)(adst + i * 8);
        const float4 a1 = *(const float4*)(adst + i * 8 + 4);
        ad8[0]=a0.x; ad8[1]=a0.y; ad8[2]=a0.z; ad8[3]=a0.w;
        ad8[4]=a1.x; ad8[5]=a1.y; ad8[6]=a1.z; ad8[7]=a1.w;
    }
    // phase A: per-head max over OWNED edges
    float m8[8];
#pragma unroll
    for (int k = 0; k < 8; k++) m8[k] = -1e30f;
    for (int e0 = wv * 64; e0 < n; e0 += 128) {
        const int e = e0 + lane;
        if (e < n) {
            const int id = (s_nb[e >> 1] >> ((e & 1) * 16)) & 0xffff;
            const float4 q0 = *(const float4*)(asrc + id * 8);
            const float4 q1 = *(const float4*)(asrc + id * 8 + 4);
            const float sv[8] = {q0.x, q0.y, q0.z, q0.w, q1.x, q1.y, q1.z, q1.w};
#pragma unroll
            for (int k = 0; k < 8; k++) m8[k] = fmaxf(m8[k], lrelu02(sv[k] + ad8[k]));
        }
    }
#pragma unroll
    for (int k = 0; k < 8; k++)
#pragma unroll
        for (int off = 32; off; off >>= 1) m8[k] = fmaxf(m8[k], __shfl_xor(m8[k], off));

    // phase B: exp vs OWN max, fp16 weights -> LDS (owned edges, pads = 0)
    float l8[8];
#pragma unroll
    for (int k = 0; k < 8; k++) l8[k] = 0.f;
    for (int e0 = wv * 64; e0 < npadE; e0 += 128) {
        const int e = e0 + lane;
        if (e < n) {
            const int id = (s_nb[e >> 1] >> ((e & 1) * 16)) & 0xffff;
            const float4 q0 = *(const float4*)(asrc + id * 8);
            const float4 q1 = *(const float4*)(asrc + id * 8 + 4);
            const float sv[8] = {q0.x, q0.y, q0.z, q0.w, q1.x, q1.y, q1.z, q1.w};
#pragma unroll
            for (int k = 0; k < 8; k++) {
                float ev = __expf(lrelu02(sv[k] + ad8[k]) - m8[k]);
                _Float16 h = (_Float16)ev;
                l8[k] += (float)h;
                s_w16[k][e] = __builtin_bit_cast(unsigned short, h);
            }
        } else if (e < npadE) {
#pragma unroll
            for (int k = 0; k < 8; k++) s_w16[k][e] = 0;
        }
    }
#pragma unroll
    for (int k = 0; k < 8; k++)
#pragma unroll
        for (int off = 32; off; off >>= 1) l8[k] += __shfl_xor(l8[k], off);

    // pass 3: gather OWNED 8-quad chunks; 2 quads (16 edges) per step with
    // all 16 loads issued before any fdot2 (deep MLP).
    const char* hb = (const char*)h1g + lane * 16;
    const unsigned* wbase = (const unsigned*)&s_w16[hd][0];
    float ac[8] = {};
    for (int q0 = wv * 8; q0 < nq; q0 += 16) {
#pragma unroll
        for (int qq = 0; qq < 8; qq += 2) {
            const int q = q0 + qq;
            const uint4 idq0 = *(const uint4*)&s_nb[q * 4];
            const uint4 idq1 = *(const uint4*)&s_nb[q * 4 + 4];
            const uint4 wq0  = *(const uint4*)(wbase + q * 4);
            const uint4 wq1  = *(const uint4*)(wbase + q * 4 + 4);
            const unsigned idv[8] = {idq0.x, idq0.y, idq0.z, idq0.w,
                                     idq1.x, idq1.y, idq1.z, idq1.w};
            const unsigned wv8[8] = {wq0.x, wq0.y, wq0.z, wq0.w,
                                     wq1.x, wq1.y, wq1.z, wq1.w};
            u4v vA[8], vB[8];
#pragma unroll
            for (int p = 0; p < 8; p++) {
                vA[p] = __builtin_nontemporal_load(
                    (const u4v*)(hb + (size_t)(idv[p] & 0xffffu) * 1024));
                vB[p] = __builtin_nontemporal_load(
                    (const u4v*)(hb + (size_t)(idv[p] >> 16) * 1024));
            }
#pragma unroll
            for (int p = 0; p < 8; p++) {
                const unsigned w = wv8[p];
                ac[0] = fdot2f(pk_lo(vA[p].x, vB[p].x), w, ac[0]);
                ac[1] = fdot2f(pk_hi(vA[p].x, vB[p].x), w, ac[1]);
                ac[2] = fdot2f(pk_lo(vA[p].y, vB[p].y), w, ac[2]);
                ac[3] = fdot2f(pk_hi(vA[p].y, vB[p].y), w, ac[3]);
                ac[4] = fdot2f(pk_lo(vA[p].z, vB[p].z), w, ac[4]);
                ac[5] = fdot2f(pk_hi(vA[p].z, vB[p].z), w, ac[5]);
                ac[6] = fdot2f(pk_lo(vA[p].w, vB[p].w), w, ac[6]);
                ac[7] = fdot2f(pk_hi(vA[p].w, vB[p].w), w, ac[7]);
            }
        }
    }
    // exchange: wave0's partial output + both waves' (m, l) per head
    if (wv == 0) {
        *(float4*)&s_comb[lane * 8]     = make_float4(ac[0], ac[1], ac[2], ac[3]);
        *(float4*)&s_comb[lane * 8 + 4] = make_float4(ac[4], ac[5], ac[6], ac[7]);
    }
    if (lane == 0) {
#pragma unroll
        for (int k = 0; k < 8; k++) {
            s_ml[wv][0][k] = m8[k];
            s_ml[wv][1][k] = l8[k];
        }
    }
    __syncthreads();
    if (wv == 1) {
        const float m0v = s_ml[0][0][hd], l0v = s_ml[0][1][hd];
        const float m1v = s_ml[1][0][hd], l1v = s_ml[1][1][hd];
        const float mm = fmaxf(m0v, m1v);
        const float a0s = __expf(m0v - mm), a1s = __expf(m1v - mm);
        const float inv = 1.0f / (l0v * a0s + l1v * a1s);
        const float4 c0 = *(const float4*)&s_comb[lane * 8];
        const float4 c1 = *(const float4*)&s_comb[lane * 8 + 4];
        const float o8[8] = {
            c0.x * a0s + ac[0] * a1s, c0.y * a0s + ac[1] * a1s,
            c0.z * a0s + ac[2] * a1s, c0.w * a0s + ac[3] * a1s,
            c1.x * a0s + ac[4] * a1s, c1.y * a0s + ac[5] * a1s,
            c1.z * a0s + ac[6] * a1s, c1.w * a0s + ac[7] * a1s };
        const float4 bb0 = *(const float4*)(b1 + lane * 8);
        const float4 bb1 = *(const float4*)(b1 + lane * 8 + 4);
        const float bbv[8] = {bb0.x, bb0.y, bb0.z, bb0.w, bb1.x, bb1.y, bb1.z, bb1.w};
        v8h ov;
#pragma unroll
        for (int c = 0; c < 8; c++)
            ov[c] = (_Float16)lrelu01(o8[c] * inv + bbv[c]);
        *(v8h*)(out1f16 + (size_t)i * 512 + lane * 8) = ov;
    }
}

// ---------------------------------------------------------------------------
// 4. Layer-2 sparse aggregate: one wave per row; 16 edges per step with 4
//    independent nt row-loads in flight per lane.
// ---------------------------------------------------------------------------
__global__ __launch_bounds__(128, 4) void attn2_kernel(
    const _Float16* __restrict__ h2g, const float* __restrict__ asrc,
    const float* __restrict__ adst, const unsigned short* __restrict__ nbr,
    const int* __restrict__ cnt, const float* __restrict__ b2,
    float* __restrict__ out) {
    const int wv   = threadIdx.x >> 6;
    const int i    = blockIdx.x * 2 + wv;
    const int lane = threadIdx.x & 63;
    const int grp  = lane >> 4, l16 = lane & 15;
    __shared__ __align__(16) unsigned s_nb[2][NPAIRS_MAX];
    __shared__ __align__(16) unsigned short s_w16[2][STRIDE + 16];

    const int n     = cnt[i];
    const int nq16  = (n + 15) >> 4;          // steps of 16 edges
    const int npad4 = nq16 * 16;
    const int npadp = npad4 >> 1;

    const unsigned* nbr32 = (const unsigned*)(nbr + (size_t)i * STRIDE);
    for (int k = lane; k < npadp; k += 64) {
        unsigned v = 0u;
        if (2 * k + 1 < n)  v = nbr32[k];
        else if (2 * k < n) v = nbr32[k] & 0xffffu;
        s_nb[wv][k] = v;
    }

    const float ad = adst[i];
    float sreg[6];
    float m = -1e30f;
#pragma unroll
    for (int it = 0; it < 6; it++) {
        const int e = it * 64 + lane;
        float s = -1e30f;
        if (e < n) {
            const int id = (s_nb[wv][e >> 1] >> ((e & 1) * 16)) & 0xffff;
            s = lrelu02(asrc[id] + ad);
        }
        sreg[it] = s;
        m = fmaxf(m, s);
    }
#pragma unroll
    for (int off = 32; off; off >>= 1) m = fmaxf(m, __shfl_xor(m, off));
    float l = 0.f;
#pragma unroll
    for (int it = 0; it < 6; it++) {
        const int e = it * 64 + lane;
        if (e < n) {
            float ev = __expf(sreg[it] - m);
            _Float16 h = (_Float16)ev;
            l += (float)h;
            s_w16[wv][e] = __builtin_bit_cast(unsigned short, h);
        }
    }
    if (lane < npad4 - n) s_w16[wv][n + lane] = 0;   // pads (<16) -> zero weight
#pragma unroll
    for (int off = 32; off; off >>= 1) l += __shfl_xor(l, off);
    const float inv = 1.0f / l;

    // gather: 16 edges per step; lane handles edge (grp + s*4), 8 ch each
    const char* hb = (const char*)h2g + l16 * 16;
    const _Float16* wtab = (const _Float16*)&s_w16[wv][0];
    float ac[8] = {};
    for (int it = 0; it < nq16; it++) {
        const int e0 = it * 16 + grp;
        unsigned idv[4]; float wv4[4]; u4v v[4];
#pragma unroll
        for (int s = 0; s < 4; s++) {
            const int e = e0 + s * 4;
            const unsigned pr = s_nb[wv][e >> 1];
            idv[s] = (e & 1) ? (pr >> 16) : (pr & 0xffffu);
            wv4[s] = (float)wtab[e];
            v[s] = __builtin_nontemporal_load(
                (const u4v*)(hb + (size_t)idv[s] * 256));
        }
#pragma unroll
        for (int s = 0; s < 4; s++) {
            const float w = wv4[s];
            ac[0] += w * f16lo(v[s].x); ac[1] += w * f16hi(v[s].x);
            ac[2] += w * f16lo(v[s].y); ac[3] += w * f16hi(v[s].y);
            ac[4] += w * f16lo(v[s].z); ac[5] += w * f16hi(v[s].z);
            ac[6] += w * f16lo(v[s].w); ac[7] += w * f16hi(v[s].w);
        }
    }
#pragma unroll
    for (int c = 0; c < 8; c++) {
        ac[c] += __shfl_xor(ac[c], 16);
        ac[c] += __shfl_xor(ac[c], 32);
    }
    if (lane < 16) {
        const float4 bb0 = *(const float4*)(b2 + lane * 8);
        const float4 bb1 = *(const float4*)(b2 + lane * 8 + 4);
        float4 o0, o1;
        o0.x = lrelu01(ac[0] * inv + bb0.x);
        o0.y = lrelu01(ac[1] * inv + bb0.y);
        o0.z = lrelu01(ac[2] * inv + bb0.z);
        o0.w = lrelu01(ac[3] * inv + bb0.w);
        o1.x = lrelu01(ac[4] * inv + bb1.x);
        o1.y = lrelu01(ac[5] * inv + bb1.y);
        o1.z = lrelu01(ac[6] * inv + bb1.z);
        o1.w = lrelu01(ac[7] * inv + bb1.w);
        *(float4*)(out + (size_t)i * 128 + lane * 8)     = o0;
        *(float4*)(out + (size_t)i * 128 + lane * 8 + 4) = o1;
    }
}

// ---------------------------------------------------------------------------
extern "C" void kernel_launch(void* const* d_in, const int* in_sizes, int n_in,
                              void* d_out, int out_size, void* d_ws, size_t ws_size,
                              hipStream_t stream) {
    const float* x        = (const float*)d_in[0];   // [4096,256]
    const float* adj      = (const float*)d_in[1];   // [4096,4096]
    const float* w1       = (const float*)d_in[2];   // [256,512]
    const float* att_src1 = (const float*)d_in[3];   // [8,64]
    const float* att_dst1 = (const float*)d_in[4];
    const float* b1       = (const float*)d_in[5];   // [512]
    const float* w2       = (const float*)d_in[6];   // [512,128]
    const float* att_src2 = (const float*)d_in[7];   // [1,128]
    const float* att_dst2 = (const float*)d_in[8];
    const float* b2       = (const float*)d_in[9];   // [128]
    float* out = (float*)d_out;                      // [4096,128]

    float* ws   = (float*)d_ws;
    float* as1  = ws;                               // 4096*8 f
    float* ad1  = as1 + 4096 * 8;                   // 4096*8 f
    float* as2  = ad1 + 4096 * 8;                   // 4096 f
    float* ad2  = as2 + 4096;                       // 4096 f
    int*   cnt  = (int*)(ad2 + 4096);               // 4096 i32
    _Float16* x16   = (_Float16*)(cnt + 4096);      // 4096*256
    _Float16* w1T   = x16 + (size_t)4096 * 256;     // 512*256
    _Float16* w2T   = w1T + 512 * 256;              // 128*512
    _Float16* h1g   = w2T + 128 * 512;              // 4096*512
    _Float16* out1h = h1g + (size_t)4096 * 512;     // 4096*512
    _Float16* h2g   = out1h + (size_t)4096 * 512;   // 4096*128
    unsigned short* nbr = (unsigned short*)(h2g + (size_t)4096 * 128); // 4096*STRIDE

    setup_kernel<<<5808, 256, 0, stream>>>(adj, nbr, cnt, x, w1, w2,
                                           x16, w1T, w2T, as2, ad2);

    // layer 1: h1 = x @ w1 (MFMA, fp16 shadow + fused direct scores)
    gemm_mfma_kernel<8, 4, 8><<<512, 256, 0, stream>>>(
        x16, w1T, h1g, att_src1, att_dst1, as1, ad1, 512);
    attn1_kernel<<<N_NODES, 128, 0, stream>>>(h1g, as1, ad1, nbr, cnt, b1, out1h);

    // layer 2: h2 = out1 @ w2 (MFMA, 512 blocks, atomic score partials)
    gemm_mfma_kernel<16, 1, 1><<<512, 256, 0, stream>>>(
        out1h, w2T, h2g, att_src2, att_dst2, as2, ad2, 128);
    attn2_kernel<<<N_NODES / 2, 128, 0, stream>>>(h2g, as2, ad2, nbr, cnt, b2, out);
}

// Round 12
// 199.973 us; speedup vs baseline: 1.3844x; 1.3844x over previous
//
#include <hip/hip_runtime.h>
#include <hip/hip_bf16.h>
#include <cstdint>

#define N_NODES 4096
#define STRIDE  384      // max degree cap (Binom(4096,0.05): mean 205, 12 sigma)
#define NPAIRS_MAX 192
#define QMAX    128      // per-quarter degree cap in build_nbr
#define WROW    400      // s_w16 head-row stride (u16): 800 B, 16B-aligned

typedef _Float16 half2v __attribute__((ext_vector_type(2)));
typedef _Float16 v4h __attribute__((ext_vector_type(4)));
typedef _Float16 v8h __attribute__((ext_vector_type(8)));
typedef float    v4f __attribute__((ext_vector_type(4)));
typedef unsigned u4v __attribute__((ext_vector_type(4)));

// ---- fp16 helpers ---------------------------------------------------------
__device__ __forceinline__ float f16lo(unsigned u) {
    half2v h = __builtin_bit_cast(half2v, u); return (float)h.x;
}
__device__ __forceinline__ float f16hi(unsigned u) {
    half2v h = __builtin_bit_cast(half2v, u); return (float)h.y;
}
__device__ __forceinline__ unsigned pk_lo(unsigned a, unsigned b) {
    return __builtin_amdgcn_perm(b, a, 0x05040100u);
}
__device__ __forceinline__ unsigned pk_hi(unsigned a, unsigned b) {
    return __builtin_amdgcn_perm(b, a, 0x07060302u);
}
__device__ __forceinline__ float fdot2f(unsigned v, unsigned w, float acc) {
    return __builtin_amdgcn_fdot2(__builtin_bit_cast(half2v, v),
                                  __builtin_bit_cast(half2v, w), acc, false);
}
__device__ __forceinline__ float lrelu02(float s) { return (s > 0.f) ? s : 0.2f * s; }
__device__ __forceinline__ float lrelu01(float s) { return (s > 0.f) ? s : 0.01f * s; }

// ---------------------------------------------------------------------------
// 1. Fused setup: neighbor-list compaction + fp16 prep + score-acc zeroing.
// ---------------------------------------------------------------------------
__global__ __launch_bounds__(256) void setup_kernel(
    const float* __restrict__ adj, unsigned short* __restrict__ nbr,
    int* __restrict__ cnt,
    const float* __restrict__ x, const float* __restrict__ w1,
    const float* __restrict__ w2, _Float16* __restrict__ x16,
    _Float16* __restrict__ w1T, _Float16* __restrict__ w2T,
    float* __restrict__ as2, float* __restrict__ ad2) {
    const int b = blockIdx.x, t = threadIdx.x;
    if (b < 4096) {
        const int i    = b;
        const int wv   = t >> 6;
        const int lane = t & 63;
        __shared__ unsigned short s_buf[4][QMAX];
        __shared__ int s_cnt[4];
        const float4* row = (const float4*)(adj + (size_t)i * N_NODES);
        int base = 0;
#pragma unroll
        for (int it = 0; it < 4; it++) {
            float4 v = row[wv * 256 + it * 64 + lane];
            float e4[4] = {v.x, v.y, v.z, v.w};
            unsigned long long m4[4];
#pragma unroll
            for (int e = 0; e < 4; e++) m4[e] = __ballot(e4[e] != 0.0f);
#pragma unroll
            for (int e = 0; e < 4; e++) {
                int prefix = __popcll(m4[e] & ((1ull << lane) - 1ull));
                int pos = base + prefix;
                if (e4[e] != 0.0f && pos < QMAX)
                    s_buf[wv][pos] = (unsigned short)(wv * 1024 + (it * 64 + lane) * 4 + e);
                base += __popcll(m4[e]);
            }
        }
        if (lane == 0) s_cnt[wv] = (base < QMAX) ? base : QMAX;
        __syncthreads();
        const int c0 = s_cnt[0], c1 = s_cnt[1], c2 = s_cnt[2], c3 = s_cnt[3];
        const int o1 = c0, o2 = c0 + c1, o3 = o2 + c2;
        int total = o3 + c3;
        if (total > STRIDE) total = STRIDE;
        for (int k = t; k < total; k += 256) {
            int w, loc;
            if      (k < o1) { w = 0; loc = k; }
            else if (k < o2) { w = 1; loc = k - o1; }
            else if (k < o3) { w = 2; loc = k - o2; }
            else             { w = 3; loc = k - o3; }
            nbr[(size_t)i * STRIDE + k] = s_buf[w][loc];
        }
        if (t == 0) cnt[i] = total;
    } else if (b < 5120) {                // x: 4096*256 elems, 4/thread
        const int idx = (b - 4096) * 1024 + t * 4;
        float4 v = *(const float4*)(x + idx);
        v4h h = { (_Float16)v.x, (_Float16)v.y, (_Float16)v.z, (_Float16)v.w };
        *(v4h*)(x16 + idx) = h;
    } else if (b < 5632) {                // w1T[512][256] <- w1[256][512]
        const int idx = (b - 5120) * 256 + t;
        const int n = idx >> 8, k = idx & 255;
        w1T[idx] = (_Float16)w1[k * 512 + n];
    } else if (b < 5792) {                // w2T[128][512] <- w2[512][128]
        const int idx = (b - 5632) * 410;
        const int e   = idx + t;
        for (int q = e; q < idx + 410 && q < 65536; q += 256) {
            const int n = q >> 9, k = q & 511;
            w2T[q] = (_Float16)w2[k * 128 + n];
        }
    } else {                              // zero as2/ad2
        const int idx = (b - 5792) * 256 + t;
        as2[idx] = 0.f;
        ad2[idx] = 0.f;
    }
}

// ---------------------------------------------------------------------------
// 2. MFMA GEMM (wave-strip over full K), fp16 in / fp32 accum; fused scores.
// ---------------------------------------------------------------------------
template<int KCH, int NSUB, int H>
__global__ __launch_bounds__(256) void gemm_mfma_kernel(
    const _Float16* __restrict__ A16, const _Float16* __restrict__ BT16,
    _Float16* __restrict__ C16,
    const float* __restrict__ att_s, const float* __restrict__ att_d,
    float* __restrict__ as_, float* __restrict__ ad_, int N) {
    const int K    = KCH * 32;
    const int wid  = blockIdx.x * 4 + (threadIdx.x >> 6);
    const int lane = threadIdx.x & 63;
    const int quad = lane >> 4, l16 = lane & 15;
    const int ntiles = N / (16 * NSUB);
    const int m0 = (wid / ntiles) * 16;
    const int n0 = (wid % ntiles) * (16 * NSUB);

    v8h a[KCH];
    const v8h* arow = (const v8h*)(A16 + (size_t)(m0 + l16) * K + quad * 8);
#pragma unroll
    for (int c = 0; c < KCH; c++) a[c] = arow[c * 4];

    float ps[4] = {}, pd[4] = {};
#pragma unroll
    for (int s = 0; s < NSUB; s++) {
        const int n = n0 + s * 16 + l16;
        const v8h* brow = (const v8h*)(BT16 + (size_t)n * K + quad * 8);
        v4f acc = {0.f, 0.f, 0.f, 0.f};
#pragma unroll
        for (int c = 0; c < KCH; c++)
            acc = __builtin_amdgcn_mfma_f32_16x16x32_f16(a[c], brow[c * 4], acc, 0, 0, 0);
        const float sa = att_s[n], sd = att_d[n];
#pragma unroll
        for (int r = 0; r < 4; r++) {
            C16[(size_t)(m0 + quad * 4 + r) * N + n] = (_Float16)acc[r];
            ps[r] += acc[r] * sa;
            pd[r] += acc[r] * sd;
        }
    }
#pragma unroll
    for (int r = 0; r < 4; r++) {
#pragma unroll
        for (int off = 1; off < 16; off <<= 1) {
            ps[r] += __shfl_xor(ps[r], off);
            pd[r] += __shfl_xor(pd[r], off);
        }
    }
    if (l16 == 0) {
#pragma unroll
        for (int r = 0; r < 4; r++) {
            const int row = m0 + quad * 4 + r;
            if (H > 1) {
                const int head = n0 >> 6;
                as_[row * H + head] = ps[r];
                ad_[row * H + head] = pd[r];
            } else {
                atomicAdd(&as_[row], ps[r]);
                atomicAdd(&ad_[row], pd[r]);
            }
        }
    }
}

// ---------------------------------------------------------------------------
// 3. Layer-1 sparse aggregate, flash-split, deep-pipelined gather (PLAIN
//    loads -- nt was a 2x regression: it evicted the L2-resident h1g).
// ---------------------------------------------------------------------------
__global__ __launch_bounds__(128, 4) void attn1_kernel(
    const _Float16* __restrict__ h1g, const float* __restrict__ asrc,
    const float* __restrict__ adst, const unsigned short* __restrict__ nbr,
    const int* __restrict__ cnt, const float* __restrict__ b1,
    _Float16* __restrict__ out1f16) {
    const int i    = blockIdx.x;
    const int wv   = threadIdx.x >> 6;
    const int lane = threadIdx.x & 63;
    const int hd   = lane >> 3;               // head of this lane (8 ch each)
    __shared__ __align__(16) unsigned s_nb[NPAIRS_MAX];
    __shared__ __align__(16) unsigned short s_w16[8][WROW];
    __shared__ __align__(16) float s_comb[512];
    __shared__ float s_ml[2][2][8];

    const int n     = cnt[i];
    const int npadE = (n + 63) & ~63;         // 64-edge multiple (<= 384)
    const int npadp = npadE >> 1;
    const int nq    = npadE >> 3;             // quads (multiple of 8)

    // stage OWNED pair chunks (32 pairs per 64-edge chunk, interleaved by wv)
    const unsigned* nbr32 = (const unsigned*)(nbr + (size_t)i * STRIDE);
    for (int k0 = wv * 32; k0 < npadp; k0 += 128) {
        const int k = k0 + (lane & 31) + ((lane >= 32) ? 64 : 0);
        if (k < npadp) {
            unsigned v = 0u;
            if (2 * k + 1 < n)  v = nbr32[k];
            else if (2 * k < n) v = nbr32[k] & 0xffffu;
            s_nb[k] = v;
        }
    }

    float ad8[8];
    {
        const float4 a0 = *(const float4*)(adst + i * 8);
        const float4 a1 = *(const float4*)(adst + i * 8 + 4);
        ad8[0]=a0.x; ad8[1]=a0.y; ad8[2]=a0.z; ad8[3]=a0.w;
        ad8[4]=a1.x; ad8[5]=a1.y; ad8[6]=a1.z; ad8[7]=a1.w;
    }
    // phase A: per-head max over OWNED edges
    float m8[8];
#pragma unroll
    for (int k = 0; k < 8; k++) m8[k] = -1e30f;
    for (int e0 = wv * 64; e0 < n; e0 += 128) {
        const int e = e0 + lane;
        if (e < n) {
            const int id = (s_nb[e >> 1] >> ((e & 1) * 16)) & 0xffff;
            const float4 q0 = *(const float4*)(asrc + id * 8);
            const float4 q1 = *(const float4*)(asrc + id * 8 + 4);
            const float sv[8] = {q0.x, q0.y, q0.z, q0.w, q1.x, q1.y, q1.z, q1.w};
#pragma unroll
            for (int k = 0; k < 8; k++) m8[k] = fmaxf(m8[k], lrelu02(sv[k] + ad8[k]));
        }
    }
#pragma unroll
    for (int k = 0; k < 8; k++)
#pragma unroll
        for (int off = 32; off; off >>= 1) m8[k] = fmaxf(m8[k], __shfl_xor(m8[k], off));

    // phase B: exp vs OWN max, fp16 weights -> LDS (owned edges, pads = 0)
    float l8[8];
#pragma unroll
    for (int k = 0; k < 8; k++) l8[k] = 0.f;
    for (int e0 = wv * 64; e0 < npadE; e0 += 128) {
        const int e = e0 + lane;
        if (e < n) {
            const int id = (s_nb[e >> 1] >> ((e & 1) * 16)) & 0xffff;
            const float4 q0 = *(const float4*)(asrc + id * 8);
            const float4 q1 = *(const float4*)(asrc + id * 8 + 4);
            const float sv[8] = {q0.x, q0.y, q0.z, q0.w, q1.x, q1.y, q1.z, q1.w};
#pragma unroll
            for (int k = 0; k < 8; k++) {
                float ev = __expf(lrelu02(sv[k] + ad8[k]) - m8[k]);
                _Float16 h = (_Float16)ev;
                l8[k] += (float)h;
                s_w16[k][e] = __builtin_bit_cast(unsigned short, h);
            }
        } else if (e < npadE) {
#pragma unroll
            for (int k = 0; k < 8; k++) s_w16[k][e] = 0;
        }
    }
#pragma unroll
    for (int k = 0; k < 8; k++)
#pragma unroll
        for (int off = 32; off; off >>= 1) l8[k] += __shfl_xor(l8[k], off);

    // pass 3: gather OWNED 8-quad chunks; 2 quads (16 edges) per step with
    // all 16 loads issued before any fdot2 (deep MLP).
    const char* hb = (const char*)h1g + lane * 16;
    const unsigned* wbase = (const unsigned*)&s_w16[hd][0];
    float ac[8] = {};
    for (int q0 = wv * 8; q0 < nq; q0 += 16) {
#pragma unroll
        for (int qq = 0; qq < 8; qq += 2) {
            const int q = q0 + qq;
            const uint4 idq0 = *(const uint4*)&s_nb[q * 4];
            const uint4 idq1 = *(const uint4*)&s_nb[q * 4 + 4];
            const uint4 wq0  = *(const uint4*)(wbase + q * 4);
            const uint4 wq1  = *(const uint4*)(wbase + q * 4 + 4);
            const unsigned idv[8] = {idq0.x, idq0.y, idq0.z, idq0.w,
                                     idq1.x, idq1.y, idq1.z, idq1.w};
            const unsigned wv8[8] = {wq0.x, wq0.y, wq0.z, wq0.w,
                                     wq1.x, wq1.y, wq1.z, wq1.w};
            u4v vA[8], vB[8];
#pragma unroll
            for (int p = 0; p < 8; p++) {
                vA[p] = *(const u4v*)(hb + (size_t)(idv[p] & 0xffffu) * 1024);
                vB[p] = *(const u4v*)(hb + (size_t)(idv[p] >> 16) * 1024);
            }
#pragma unroll
            for (int p = 0; p < 8; p++) {
                const unsigned w = wv8[p];
                ac[0] = fdot2f(pk_lo(vA[p].x, vB[p].x), w, ac[0]);
                ac[1] = fdot2f(pk_hi(vA[p].x, vB[p].x), w, ac[1]);
                ac[2] = fdot2f(pk_lo(vA[p].y, vB[p].y), w, ac[2]);
                ac[3] = fdot2f(pk_hi(vA[p].y, vB[p].y), w, ac[3]);
                ac[4] = fdot2f(pk_lo(vA[p].z, vB[p].z), w, ac[4]);
                ac[5] = fdot2f(pk_hi(vA[p].z, vB[p].z), w, ac[5]);
                ac[6] = fdot2f(pk_lo(vA[p].w, vB[p].w), w, ac[6]);
                ac[7] = fdot2f(pk_hi(vA[p].w, vB[p].w), w, ac[7]);
            }
        }
    }
    // exchange: wave0's partial output + both waves' (m, l) per head
    if (wv == 0) {
        *(float4*)&s_comb[lane * 8]     = make_float4(ac[0], ac[1], ac[2], ac[3]);
        *(float4*)&s_comb[lane * 8 + 4] = make_float4(ac[4], ac[5], ac[6], ac[7]);
    }
    if (lane == 0) {
#pragma unroll
        for (int k = 0; k < 8; k++) {
            s_ml[wv][0][k] = m8[k];
            s_ml[wv][1][k] = l8[k];
        }
    }
    __syncthreads();
    if (wv == 1) {
        const float m0v = s_ml[0][0][hd], l0v = s_ml[0][1][hd];
        const float m1v = s_ml[1][0][hd], l1v = s_ml[1][1][hd];
        const float mm = fmaxf(m0v, m1v);
        const float a0s = __expf(m0v - mm), a1s = __expf(m1v - mm);
        const float inv = 1.0f / (l0v * a0s + l1v * a1s);
        const float4 c0 = *(const float4*)&s_comb[lane * 8];
        const float4 c1 = *(const float4*)&s_comb[lane * 8 + 4];
        const float o8[8] = {
            c0.x * a0s + ac[0] * a1s, c0.y * a0s + ac[1] * a1s,
            c0.z * a0s + ac[2] * a1s, c0.w * a0s + ac[3] * a1s,
            c1.x * a0s + ac[4] * a1s, c1.y * a0s + ac[5] * a1s,
            c1.z * a0s + ac[6] * a1s, c1.w * a0s + ac[7] * a1s };
        const float4 bb0 = *(const float4*)(b1 + lane * 8);
        const float4 bb1 = *(const float4*)(b1 + lane * 8 + 4);
        const float bbv[8] = {bb0.x, bb0.y, bb0.z, bb0.w, bb1.x, bb1.y, bb1.z, bb1.w};
        v8h ov;
#pragma unroll
        for (int c = 0; c < 8; c++)
            ov[c] = (_Float16)lrelu01(o8[c] * inv + bbv[c]);
        *(v8h*)(out1f16 + (size_t)i * 512 + lane * 8) = ov;
    }
}

// ---------------------------------------------------------------------------
// 4. Layer-2 sparse aggregate: one wave per row; 16 edges per step with 4
//    independent row-loads in flight per lane (plain loads).
// ---------------------------------------------------------------------------
__global__ __launch_bounds__(128, 4) void attn2_kernel(
    const _Float16* __restrict__ h2g, const float* __restrict__ asrc,
    const float* __restrict__ adst, const unsigned short* __restrict__ nbr,
    const int* __restrict__ cnt, const float* __restrict__ b2,
    float* __restrict__ out) {
    const int wv   = threadIdx.x >> 6;
    const int i    = blockIdx.x * 2 + wv;
    const int lane = threadIdx.x & 63;
    const int grp  = lane >> 4, l16 = lane & 15;
    __shared__ __align__(16) unsigned s_nb[2][NPAIRS_MAX];
    __shared__ __align__(16) unsigned short s_w16[2][STRIDE + 16];

    const int n     = cnt[i];
    const int nq16  = (n + 15) >> 4;          // steps of 16 edges
    const int npad4 = nq16 * 16;
    const int npadp = npad4 >> 1;

    const unsigned* nbr32 = (const unsigned*)(nbr + (size_t)i * STRIDE);
    for (int k = lane; k < npadp; k += 64) {
        unsigned v = 0u;
        if (2 * k + 1 < n)  v = nbr32[k];
        else if (2 * k < n) v = nbr32[k] & 0xffffu;
        s_nb[wv][k] = v;
    }

    const float ad = adst[i];
    float sreg[6];
    float m = -1e30f;
#pragma unroll
    for (int it = 0; it < 6; it++) {
        const int e = it * 64 + lane;
        float s = -1e30f;
        if (e < n) {
            const int id = (s_nb[wv][e >> 1] >> ((e & 1) * 16)) & 0xffff;
            s = lrelu02(asrc[id] + ad);
        }
        sreg[it] = s;
        m = fmaxf(m, s);
    }
#pragma unroll
    for (int off = 32; off; off >>= 1) m = fmaxf(m, __shfl_xor(m, off));
    float l = 0.f;
#pragma unroll
    for (int it = 0; it < 6; it++) {
        const int e = it * 64 + lane;
        if (e < n) {
            float ev = __expf(sreg[it] - m);
            _Float16 h = (_Float16)ev;
            l += (float)h;
            s_w16[wv][e] = __builtin_bit_cast(unsigned short, h);
        }
    }
    if (lane < npad4 - n) s_w16[wv][n + lane] = 0;   // pads (<16) -> zero weight
#pragma unroll
    for (int off = 32; off; off >>= 1) l += __shfl_xor(l, off);
    const float inv = 1.0f / l;

    // gather: 16 edges per step; lane handles edge (grp + s*4), 8 ch each
    const char* hb = (const char*)h2g + l16 * 16;
    const _Float16* wtab = (const _Float16*)&s_w16[wv][0];
    float ac[8] = {};
    for (int it = 0; it < nq16; it++) {
        const int e0 = it * 16 + grp;
        unsigned idv[4]; float wv4[4]; u4v v[4];
#pragma unroll
        for (int s = 0; s < 4; s++) {
            const int e = e0 + s * 4;
            const unsigned pr = s_nb[wv][e >> 1];
            idv[s] = (e & 1) ? (pr >> 16) : (pr & 0xffffu);
            wv4[s] = (float)wtab[e];
            v[s] = *(const u4v*)(hb + (size_t)idv[s] * 256);
        }
#pragma unroll
        for (int s = 0; s < 4; s++) {
            const float w = wv4[s];
            ac[0] += w * f16lo(v[s].x); ac[1] += w * f16hi(v[s].x);
            ac[2] += w * f16lo(v[s].y); ac[3] += w * f16hi(v[s].y);
            ac[4] += w * f16lo(v[s].z); ac[5] += w * f16hi(v[s].z);
            ac[6] += w * f16lo(v[s].w); ac[7] += w * f16hi(v[s].w);
        }
    }
#pragma unroll
    for (int c = 0; c < 8; c++) {
        ac[c] += __shfl_xor(ac[c], 16);
        ac[c] += __shfl_xor(ac[c], 32);
    }
    if (lane < 16) {
        const float4 bb0 = *(const float4*)(b2 + lane * 8);
        const float4 bb1 = *(const float4*)(b2 + lane * 8 + 4);
        float4 o0, o1;
        o0.x = lrelu01(ac[0] * inv + bb0.x);
        o0.y = lrelu01(ac[1] * inv + bb0.y);
        o0.z = lrelu01(ac[2] * inv + bb0.z);
        o0.w = lrelu01(ac[3] * inv + bb0.w);
        o1.x = lrelu01(ac[4] * inv + bb1.x);
        o1.y = lrelu01(ac[5] * inv + bb1.y);
        o1.z = lrelu01(ac[6] * inv + bb1.z);
        o1.w = lrelu01(ac[7] * inv + bb1.w);
        *(float4*)(out + (size_t)i * 128 + lane * 8)     = o0;
        *(float4*)(out + (size_t)i * 128 + lane * 8 + 4) = o1;
    }
}

// ---------------------------------------------------------------------------
extern "C" void kernel_launch(void* const* d_in, const int* in_sizes, int n_in,
                              void* d_out, int out_size, void* d_ws, size_t ws_size,
                              hipStream_t stream) {
    const float* x        = (const float*)d_in[0];   // [4096,256]
    const float* adj      = (const float*)d_in[1];   // [4096,4096]
    const float* w1       = (const float*)d_in[2];   // [256,512]
    const float* att_src1 = (const float*)d_in[3];   // [8,64]
    const float* att_dst1 = (const float*)d_in[4];
    const float* b1       = (const float*)d_in[5];   // [512]
    const float* w2       = (const float*)d_in[6];   // [512,128]
    const float* att_src2 = (const float*)d_in[7];   // [1,128]
    const float* att_dst2 = (const float*)d_in[8];
    const float* b2       = (const float*)d_in[9];   // [128]
    float* out = (float*)d_out;                      // [4096,128]

    float* ws   = (float*)d_ws;
    float* as1  = ws;                               // 4096*8 f
    float* ad1  = as1 + 4096 * 8;                   // 4096*8 f
    float* as2  = ad1 + 4096 * 8;                   // 4096 f
    float* ad2  = as2 + 4096;                       // 4096 f
    int*   cnt  = (int*)(ad2 + 4096);               // 4096 i32
    _Float16* x16   = (_Float16*)(cnt + 4096);      // 4096*256
    _Float16* w1T   = x16 + (size_t)4096 * 256;     // 512*256
    _Float16* w2T   = w1T + 512 * 256;              // 128*512
    _Float16* h1g   = w2T + 128 * 512;              // 4096*512
    _Float16* out1h = h1g + (size_t)4096 * 512;     // 4096*512
    _Float16* h2g   = out1h + (size_t)4096 * 512;   // 4096*128
    unsigned short* nbr = (unsigned short*)(h2g + (size_t)4096 * 128); // 4096*STRIDE

    setup_kernel<<<5808, 256, 0, stream>>>(adj, nbr, cnt, x, w1, w2,
                                           x16, w1T, w2T, as2, ad2);

    // layer 1: h1 = x @ w1 (MFMA, fp16 shadow + fused direct scores)
    gemm_mfma_kernel<8, 4, 8><<<512, 256, 0, stream>>>(
        x16, w1T, h1g, att_src1, att_dst1, as1, ad1, 512);
    attn1_kernel<<<N_NODES, 128, 0, stream>>>(h1g, as1, ad1, nbr, cnt, b1, out1h);

    // layer 2: h2 = out1 @ w2 (MFMA, 512 blocks, atomic score partials)
    gemm_mfma_kernel<16, 1, 1><<<512, 256, 0, stream>>>(
        out1h, w2T, h2g, att_src2, att_dst2, as2, ad2, 128);
    attn2_kernel<<<N_NODES / 2, 128, 0, stream>>>(h2g, as2, ad2, nbr, cnt, b2, out);
}

// Round 13
// 194.878 us; speedup vs baseline: 1.4206x; 1.0261x over previous
//
#include <hip/hip_runtime.h>
#include <hip/hip_bf16.h>
#include <cstdint>

#define N_NODES 4096
#define STRIDE  384      // max degree cap (Binom(4096,0.05): mean 205, 12 sigma)
#define NPAIRS_MAX 192
#define QMAX    128      // per-quarter degree cap in build_nbr
#define WROW    400      // s_w16 head-row stride (u16): 800 B, 16B-aligned

typedef _Float16 half2v __attribute__((ext_vector_type(2)));
typedef _Float16 v4h __attribute__((ext_vector_type(4)));
typedef _Float16 v8h __attribute__((ext_vector_type(8)));
typedef float    v4f __attribute__((ext_vector_type(4)));
typedef unsigned u4v __attribute__((ext_vector_type(4)));

// ---- fp16 helpers ---------------------------------------------------------
__device__ __forceinline__ float f16lo(unsigned u) {
    half2v h = __builtin_bit_cast(half2v, u); return (float)h.x;
}
__device__ __forceinline__ float f16hi(unsigned u) {
    half2v h = __builtin_bit_cast(half2v, u); return (float)h.y;
}
__device__ __forceinline__ unsigned pk_lo(unsigned a, unsigned b) {
    return __builtin_amdgcn_perm(b, a, 0x05040100u);
}
__device__ __forceinline__ unsigned pk_hi(unsigned a, unsigned b) {
    return __builtin_amdgcn_perm(b, a, 0x07060302u);
}
__device__ __forceinline__ float fdot2f(unsigned v, unsigned w, float acc) {
    return __builtin_amdgcn_fdot2(__builtin_bit_cast(half2v, v),
                                  __builtin_bit_cast(half2v, w), acc, false);
}
__device__ __forceinline__ float lrelu02(float s) { return (s > 0.f) ? s : 0.2f * s; }
__device__ __forceinline__ float lrelu01(float s) { return (s > 0.f) ? s : 0.01f * s; }

// ---------------------------------------------------------------------------
// 1. Fused setup: neighbor-list compaction + w1T/w2T fp16 transposes +
//    score-acc zeroing. (x is converted on the fly inside gemm1 now.)
// ---------------------------------------------------------------------------
__global__ __launch_bounds__(256) void setup_kernel(
    const float* __restrict__ adj, unsigned short* __restrict__ nbr,
    int* __restrict__ cnt,
    const float* __restrict__ w1, const float* __restrict__ w2,
    _Float16* __restrict__ w1T, _Float16* __restrict__ w2T,
    float* __restrict__ as2, float* __restrict__ ad2) {
    const int b = blockIdx.x, t = threadIdx.x;
    if (b < 4096) {
        const int i    = b;
        const int wv   = t >> 6;
        const int lane = t & 63;
        __shared__ unsigned short s_buf[4][QMAX];
        __shared__ int s_cnt[4];
        const float4* row = (const float4*)(adj + (size_t)i * N_NODES);
        int base = 0;
#pragma unroll
        for (int it = 0; it < 4; it++) {
            float4 v = row[wv * 256 + it * 64 + lane];
            float e4[4] = {v.x, v.y, v.z, v.w};
            unsigned long long m4[4];
#pragma unroll
            for (int e = 0; e < 4; e++) m4[e] = __ballot(e4[e] != 0.0f);
#pragma unroll
            for (int e = 0; e < 4; e++) {
                int prefix = __popcll(m4[e] & ((1ull << lane) - 1ull));
                int pos = base + prefix;
                if (e4[e] != 0.0f && pos < QMAX)
                    s_buf[wv][pos] = (unsigned short)(wv * 1024 + (it * 64 + lane) * 4 + e);
                base += __popcll(m4[e]);
            }
        }
        if (lane == 0) s_cnt[wv] = (base < QMAX) ? base : QMAX;
        __syncthreads();
        const int c0 = s_cnt[0], c1 = s_cnt[1], c2 = s_cnt[2], c3 = s_cnt[3];
        const int o1 = c0, o2 = c0 + c1, o3 = o2 + c2;
        int total = o3 + c3;
        if (total > STRIDE) total = STRIDE;
        for (int k = t; k < total; k += 256) {
            int w, loc;
            if      (k < o1) { w = 0; loc = k; }
            else if (k < o2) { w = 1; loc = k - o1; }
            else if (k < o3) { w = 2; loc = k - o2; }
            else             { w = 3; loc = k - o3; }
            nbr[(size_t)i * STRIDE + k] = s_buf[w][loc];
        }
        if (t == 0) cnt[i] = total;
    } else if (b < 4608) {                // w1T[512][256] <- w1[256][512]
        const int idx = (b - 4096) * 256 + t;
        const int n = idx >> 8, k = idx & 255;
        w1T[idx] = (_Float16)w1[k * 512 + n];
    } else if (b < 4768) {                // w2T[128][512] <- w2[512][128]
        const int idx = (b - 4608) * 410;
        const int e   = idx + t;
        for (int q = e; q < idx + 410 && q < 65536; q += 256) {
            const int n = q >> 9, k = q & 511;
            w2T[q] = (_Float16)w2[k * 128 + n];
        }
    } else {                              // zero as2/ad2
        const int idx = (b - 4768) * 256 + t;
        as2[idx] = 0.f;
        ad2[idx] = 0.f;
    }
}

// ---------------------------------------------------------------------------
// 2. MFMA GEMM (wave-strip over full K), fp16 in / fp32 accum; fused scores.
//    AF32=true: A operand is fp32, converted RNE to fp16 fragments on the fly.
// ---------------------------------------------------------------------------
template<int KCH, int NSUB, int H, bool AF32>
__global__ __launch_bounds__(256) void gemm_mfma_kernel(
    const void* __restrict__ Aptr, const _Float16* __restrict__ BT16,
    _Float16* __restrict__ C16,
    const float* __restrict__ att_s, const float* __restrict__ att_d,
    float* __restrict__ as_, float* __restrict__ ad_, int N) {
    const int K    = KCH * 32;
    const int wid  = blockIdx.x * 4 + (threadIdx.x >> 6);
    const int lane = threadIdx.x & 63;
    const int quad = lane >> 4, l16 = lane & 15;
    const int ntiles = N / (16 * NSUB);
    const int m0 = (wid / ntiles) * 16;
    const int n0 = (wid % ntiles) * (16 * NSUB);

    v8h a[KCH];
    if constexpr (AF32) {
        const float* ax = (const float*)Aptr + (size_t)(m0 + l16) * K + quad * 8;
#pragma unroll
        for (int c = 0; c < KCH; c++) {
            const float4 p = *(const float4*)(ax + c * 32);
            const float4 q = *(const float4*)(ax + c * 32 + 4);
            v8h h;
            h[0] = (_Float16)p.x; h[1] = (_Float16)p.y;
            h[2] = (_Float16)p.z; h[3] = (_Float16)p.w;
            h[4] = (_Float16)q.x; h[5] = (_Float16)q.y;
            h[6] = (_Float16)q.z; h[7] = (_Float16)q.w;
            a[c] = h;
        }
    } else {
        const v8h* arow = (const v8h*)((const _Float16*)Aptr +
                                       (size_t)(m0 + l16) * K + quad * 8);
#pragma unroll
        for (int c = 0; c < KCH; c++) a[c] = arow[c * 4];
    }

    float ps[4] = {}, pd[4] = {};
#pragma unroll
    for (int s = 0; s < NSUB; s++) {
        const int n = n0 + s * 16 + l16;
        const v8h* brow = (const v8h*)(BT16 + (size_t)n * K + quad * 8);
        v4f acc = {0.f, 0.f, 0.f, 0.f};
#pragma unroll
        for (int c = 0; c < KCH; c++)
            acc = __builtin_amdgcn_mfma_f32_16x16x32_f16(a[c], brow[c * 4], acc, 0, 0, 0);
        const float sa = att_s[n], sd = att_d[n];
#pragma unroll
        for (int r = 0; r < 4; r++) {
            C16[(size_t)(m0 + quad * 4 + r) * N + n] = (_Float16)acc[r];
            ps[r] += acc[r] * sa;
            pd[r] += acc[r] * sd;
        }
    }
#pragma unroll
    for (int r = 0; r < 4; r++) {
#pragma unroll
        for (int off = 1; off < 16; off <<= 1) {
            ps[r] += __shfl_xor(ps[r], off);
            pd[r] += __shfl_xor(pd[r], off);
        }
    }
    if (l16 == 0) {
#pragma unroll
        for (int r = 0; r < 4; r++) {
            const int row = m0 + quad * 4 + r;
            if (H > 1) {
                const int head = n0 >> 6;
                as_[row * H + head] = ps[r];
                ad_[row * H + head] = pd[r];
            } else {
                atomicAdd(&as_[row], ps[r]);
                atomicAdd(&ad_[row], pd[r]);
            }
        }
    }
}

// ---------------------------------------------------------------------------
// 3. Layer-1 sparse aggregate (R9 structure, best measured: 49.1 us).
//    Flash-split: one block (2 waves) per row; wave owns alternating 64-edge
//    chunks; partial max/weights/denominator/output; one barrier; exact
//    fp32 rescale combine.
// ---------------------------------------------------------------------------
__global__ __launch_bounds__(128) void attn1_kernel(
    const _Float16* __restrict__ h1g, const float* __restrict__ asrc,
    const float* __restrict__ adst, const unsigned short* __restrict__ nbr,
    const int* __restrict__ cnt, const float* __restrict__ b1,
    _Float16* __restrict__ out1f16) {
    const int i    = blockIdx.x;
    const int wv   = threadIdx.x >> 6;
    const int lane = threadIdx.x & 63;
    const int hd   = lane >> 3;               // head of this lane (8 ch each)
    __shared__ __align__(16) unsigned s_nb[NPAIRS_MAX];
    __shared__ __align__(16) unsigned short s_w16[8][WROW];
    __shared__ __align__(16) float s_comb[512];
    __shared__ float s_ml[2][2][8];

    const int n      = cnt[i];
    const int npairs = (n + 1) >> 1;
    const int nq     = (npairs + 3) >> 2;     // pair-quads (8 edges each)
    const int npadp  = nq * 4;
    const int npadE  = npadp * 2;

    // stage OWNED pair chunks (32 pairs per 64-edge chunk, interleaved by wv)
    const unsigned* nbr32 = (const unsigned*)(nbr + (size_t)i * STRIDE);
    for (int k0 = wv * 32; k0 < npadp; k0 += 128) {
        const int k = k0 + (lane & 31) + ((lane >= 32) ? 64 : 0);
        if (k < npadp) {
            unsigned v = 0u;
            if (2 * k + 1 < n)  v = nbr32[k];
            else if (2 * k < n) v = nbr32[k] & 0xffffu;
            s_nb[k] = v;
        }
    }

    float ad8[8];
    {
        const float4 a0 = *(const float4*)(adst + i * 8);
        const float4 a1 = *(const float4*)(adst + i * 8 + 4);
        ad8[0]=a0.x; ad8[1]=a0.y; ad8[2]=a0.z; ad8[3]=a0.w;
        ad8[4]=a1.x; ad8[5]=a1.y; ad8[6]=a1.z; ad8[7]=a1.w;
    }
    // phase A: per-head max over OWNED edges
    float m8[8];
#pragma unroll
    for (int k = 0; k < 8; k++) m8[k] = -1e30f;
    for (int e0 = wv * 64; e0 < n; e0 += 128) {
        const int e = e0 + lane;
        if (e < n) {
            const int id = (s_nb[e >> 1] >> ((e & 1) * 16)) & 0xffff;
            const float4 q0 = *(const float4*)(asrc + id * 8);
            const float4 q1 = *(const float4*)(asrc + id * 8 + 4);
            const float sv[8] = {q0.x, q0.y, q0.z, q0.w, q1.x, q1.y, q1.z, q1.w};
#pragma unroll
            for (int k = 0; k < 8; k++) m8[k] = fmaxf(m8[k], lrelu02(sv[k] + ad8[k]));
        }
    }
#pragma unroll
    for (int k = 0; k < 8; k++)
#pragma unroll
        for (int off = 32; off; off >>= 1) m8[k] = fmaxf(m8[k], __shfl_xor(m8[k], off));

    // phase B: exp vs OWN max, fp16 weights -> LDS (owned edges, pads = 0)
    float l8[8];
#pragma unroll
    for (int k = 0; k < 8; k++) l8[k] = 0.f;
    for (int e0 = wv * 64; e0 < npadE; e0 += 128) {
        const int e = e0 + lane;
        if (e < n) {
            const int id = (s_nb[e >> 1] >> ((e & 1) * 16)) & 0xffff;
            const float4 q0 = *(const float4*)(asrc + id * 8);
            const float4 q1 = *(const float4*)(asrc + id * 8 + 4);
            const float sv[8] = {q0.x, q0.y, q0.z, q0.w, q1.x, q1.y, q1.z, q1.w};
#pragma unroll
            for (int k = 0; k < 8; k++) {
                float ev = __expf(lrelu02(sv[k] + ad8[k]) - m8[k]);
                _Float16 h = (_Float16)ev;
                l8[k] += (float)h;
                s_w16[k][e] = __builtin_bit_cast(unsigned short, h);
            }
        } else if (e < npadE) {
#pragma unroll
            for (int k = 0; k < 8; k++) s_w16[k][e] = 0;
        }
    }
#pragma unroll
    for (int k = 0; k < 8; k++)
#pragma unroll
        for (int off = 32; off; off >>= 1) l8[k] += __shfl_xor(l8[k], off);

    // pass 3: gather OWNED quads (8 per 128-edge superchunk, interleaved).
    const char* hb = (const char*)h1g + lane * 16;
    const unsigned* wbase = (const unsigned*)&s_w16[hd][0];
    float ac[8] = {};
    for (int q0 = wv * 8; q0 < nq; q0 += 16) {
#pragma unroll
        for (int qq = 0; qq < 8; qq++) {
            const int q = q0 + qq;
            if (q >= nq) break;
            const uint4 idq = *(const uint4*)&s_nb[q * 4];
            const uint4 wq  = *(const uint4*)(wbase + q * 4);
            const unsigned idv[4] = {idq.x, idq.y, idq.z, idq.w};
            const unsigned wv4[4] = {wq.x, wq.y, wq.z, wq.w};
#pragma unroll
            for (int p = 0; p < 4; p++) {
                const int iA = idv[p] & 0xffff, iB = idv[p] >> 16;
                const uint4 vA = *(const uint4*)(hb + (size_t)iA * 1024);
                const uint4 vB = *(const uint4*)(hb + (size_t)iB * 1024);
                const unsigned w = wv4[p];
                ac[0] = fdot2f(pk_lo(vA.x, vB.x), w, ac[0]);
                ac[1] = fdot2f(pk_hi(vA.x, vB.x), w, ac[1]);
                ac[2] = fdot2f(pk_lo(vA.y, vB.y), w, ac[2]);
                ac[3] = fdot2f(pk_hi(vA.y, vB.y), w, ac[3]);
                ac[4] = fdot2f(pk_lo(vA.z, vB.z), w, ac[4]);
                ac[5] = fdot2f(pk_hi(vA.z, vB.z), w, ac[5]);
                ac[6] = fdot2f(pk_lo(vA.w, vB.w), w, ac[6]);
                ac[7] = fdot2f(pk_hi(vA.w, vB.w), w, ac[7]);
            }
        }
    }
    // exchange: wave0's partial output + both waves' (m, l) per head
    if (wv == 0) {
        *(float4*)&s_comb[lane * 8]     = make_float4(ac[0], ac[1], ac[2], ac[3]);
        *(float4*)&s_comb[lane * 8 + 4] = make_float4(ac[4], ac[5], ac[6], ac[7]);
    }
    if (lane == 0) {
#pragma unroll
        for (int k = 0; k < 8; k++) {
            s_ml[wv][0][k] = m8[k];
            s_ml[wv][1][k] = l8[k];
        }
    }
    __syncthreads();
    if (wv == 1) {
        const float m0v = s_ml[0][0][hd], l0v = s_ml[0][1][hd];
        const float m1v = s_ml[1][0][hd], l1v = s_ml[1][1][hd];
        const float mm = fmaxf(m0v, m1v);
        const float a0s = __expf(m0v - mm), a1s = __expf(m1v - mm);
        const float inv = 1.0f / (l0v * a0s + l1v * a1s);
        const float4 c0 = *(const float4*)&s_comb[lane * 8];
        const float4 c1 = *(const float4*)&s_comb[lane * 8 + 4];
        const float o8[8] = {
            c0.x * a0s + ac[0] * a1s, c0.y * a0s + ac[1] * a1s,
            c0.z * a0s + ac[2] * a1s, c0.w * a0s + ac[3] * a1s,
            c1.x * a0s + ac[4] * a1s, c1.y * a0s + ac[5] * a1s,
            c1.z * a0s + ac[6] * a1s, c1.w * a0s + ac[7] * a1s };
        const float4 bb0 = *(const float4*)(b1 + lane * 8);
        const float4 bb1 = *(const float4*)(b1 + lane * 8 + 4);
        const float bbv[8] = {bb0.x, bb0.y, bb0.z, bb0.w, bb1.x, bb1.y, bb1.z, bb1.w};
        v8h ov;
#pragma unroll
        for (int c = 0; c < 8; c++)
            ov[c] = (_Float16)lrelu01(o8[c] * inv + bbv[c]);
        *(v8h*)(out1f16 + (size_t)i * 512 + lane * 8) = ov;
    }
}

// ---------------------------------------------------------------------------
// 4. Layer-2 sparse aggregate (R9 structure): one wave per row, 4 edges per
//    gather inst (lane group g carries edge g; 16 lanes x 16B = full row).
// ---------------------------------------------------------------------------
__global__ __launch_bounds__(128) void attn2_kernel(
    const _Float16* __restrict__ h2g, const float* __restrict__ asrc,
    const float* __restrict__ adst, const unsigned short* __restrict__ nbr,
    const int* __restrict__ cnt, const float* __restrict__ b2,
    float* __restrict__ out) {
    const int wv   = threadIdx.x >> 6;
    const int i    = blockIdx.x * 2 + wv;
    const int lane = threadIdx.x & 63;
    const int grp  = lane >> 4, l16 = lane & 15;
    __shared__ __align__(16) unsigned s_nb[2][NPAIRS_MAX];
    __shared__ __align__(16) unsigned short s_w16[2][STRIDE + 16];

    const int n     = cnt[i];
    const int nq4   = (n + 3) >> 2;           // edge-quads
    const int npad4 = nq4 * 4;
    const int npadp = (npad4 + 1) >> 1;

    const unsigned* nbr32 = (const unsigned*)(nbr + (size_t)i * STRIDE);
    for (int k = lane; k < npadp; k += 64) {
        unsigned v = 0u;
        if (2 * k + 1 < n)  v = nbr32[k];
        else if (2 * k < n) v = nbr32[k] & 0xffffu;
        s_nb[wv][k] = v;
    }

    const float ad = adst[i];
    float sreg[6];
    float m = -1e30f;
#pragma unroll
    for (int it = 0; it < 6; it++) {
        const int e = it * 64 + lane;
        float s = -1e30f;
        if (e < n) {
            const int id = (s_nb[wv][e >> 1] >> ((e & 1) * 16)) & 0xffff;
            s = lrelu02(asrc[id] + ad);
        }
        sreg[it] = s;
        m = fmaxf(m, s);
    }
#pragma unroll
    for (int off = 32; off; off >>= 1) m = fmaxf(m, __shfl_xor(m, off));
    float l = 0.f;
#pragma unroll
    for (int it = 0; it < 6; it++) {
        const int e = it * 64 + lane;
        if (e < n) {
            float ev = __expf(sreg[it] - m);
            _Float16 h = (_Float16)ev;
            l += (float)h;
            s_w16[wv][e] = __builtin_bit_cast(unsigned short, h);
        }
    }
    if (lane < npad4 - n) s_w16[wv][n + lane] = 0;
#pragma unroll
    for (int off = 32; off; off >>= 1) l += __shfl_xor(l, off);
    const float inv = 1.0f / l;

    // gather: 4 edges per iteration; lane loads 16B (8 ch) of edge `grp`
    const char* hb = (const char*)h2g + l16 * 16;
    float ac[8] = {};
    for (int it = 0; it < nq4; it++) {
        const int e = it * 4 + grp;
        const unsigned pr = s_nb[wv][e >> 1];
        const int id = (e & 1) ? (int)(pr >> 16) : (int)(pr & 0xffffu);
        const float w = (float)((const _Float16*)&s_w16[wv][0])[e];
        const uint4 v = *(const uint4*)(hb + (size_t)id * 256);
        ac[0] += w * f16lo(v.x); ac[1] += w * f16hi(v.x);
        ac[2] += w * f16lo(v.y); ac[3] += w * f16hi(v.y);
        ac[4] += w * f16lo(v.z); ac[5] += w * f16hi(v.z);
        ac[6] += w * f16lo(v.w); ac[7] += w * f16hi(v.w);
    }
#pragma unroll
    for (int c = 0; c < 8; c++) {
        ac[c] += __shfl_xor(ac[c], 16);
        ac[c] += __shfl_xor(ac[c], 32);
    }
    if (lane < 16) {
        const float4 bb0 = *(const float4*)(b2 + lane * 8);
        const float4 bb1 = *(const float4*)(b2 + lane * 8 + 4);
        float4 o0, o1;
        o0.x = lrelu01(ac[0] * inv + bb0.x);
        o0.y = lrelu01(ac[1] * inv + bb0.y);
        o0.z = lrelu01(ac[2] * inv + bb0.z);
        o0.w = lrelu01(ac[3] * inv + bb0.w);
        o1.x = lrelu01(ac[4] * inv + bb1.x);
        o1.y = lrelu01(ac[5] * inv + bb1.y);
        o1.z = lrelu01(ac[6] * inv + bb1.z);
        o1.w = lrelu01(ac[7] * inv + bb1.w);
        *(float4*)(out + (size_t)i * 128 + lane * 8)     = o0;
        *(float4*)(out + (size_t)i * 128 + lane * 8 + 4) = o1;
    }
}

// ---------------------------------------------------------------------------
extern "C" void kernel_launch(void* const* d_in, const int* in_sizes, int n_in,
                              void* d_out, int out_size, void* d_ws, size_t ws_size,
                              hipStream_t stream) {
    const float* x        = (const float*)d_in[0];   // [4096,256]
    const float* adj      = (const float*)d_in[1];   // [4096,4096]
    const float* w1       = (const float*)d_in[2];   // [256,512]
    const float* att_src1 = (const float*)d_in[3];   // [8,64]
    const float* att_dst1 = (const float*)d_in[4];
    const float* b1       = (const float*)d_in[5];   // [512]
    const float* w2       = (const float*)d_in[6];   // [512,128]
    const float* att_src2 = (const float*)d_in[7];   // [1,128]
    const float* att_dst2 = (const float*)d_in[8];
    const float* b2       = (const float*)d_in[9];   // [128]
    float* out = (float*)d_out;                      // [4096,128]

    float* ws   = (float*)d_ws;
    float* as1  = ws;                               // 4096*8 f
    float* ad1  = as1 + 4096 * 8;                   // 4096*8 f
    float* as2  = ad1 + 4096 * 8;                   // 4096 f
    float* ad2  = as2 + 4096;                       // 4096 f
    int*   cnt  = (int*)(ad2 + 4096);               // 4096 i32
    _Float16* w1T   = (_Float16*)(cnt + 4096);      // 512*256
    _Float16* w2T   = w1T + 512 * 256;              // 128*512
    _Float16* h1g   = w2T + 128 * 512;              // 4096*512
    _Float16* out1h = h1g + (size_t)4096 * 512;     // 4096*512
    _Float16* h2g   = out1h + (size_t)4096 * 512;   // 4096*128
    unsigned short* nbr = (unsigned short*)(h2g + (size_t)4096 * 128); // 4096*STRIDE

    setup_kernel<<<4784, 256, 0, stream>>>(adj, nbr, cnt, w1, w2,
                                           w1T, w2T, as2, ad2);

    // layer 1: h1 = x @ w1 (MFMA, on-the-fly fp32->fp16 A, fused scores)
    gemm_mfma_kernel<8, 4, 8, true><<<512, 256, 0, stream>>>(
        x, w1T, h1g, att_src1, att_dst1, as1, ad1, 512);
    attn1_kernel<<<N_NODES, 128, 0, stream>>>(h1g, as1, ad1, nbr, cnt, b1, out1h);

    // layer 2: h2 = out1 @ w2 (MFMA, atomic score partials)
    gemm_mfma_kernel<16, 2, 1, false><<<256, 256, 0, stream>>>(
        out1h, w2T, h2g, att_src2, att_dst2, as2, ad2, 128);
    attn2_kernel<<<N_NODES / 2, 128, 0, stream>>>(h2g, as2, ad2, nbr, cnt, b2, out);
}